// Round 7
// baseline (671.212 us; speedup 1.0000x reference)
//
#include <hip/hip_runtime.h>
#include <cstdint>
#include <cstddef>

typedef unsigned short u16;
typedef __attribute__((ext_vector_type(8))) short short8;
typedef __attribute__((ext_vector_type(4))) float floatx4;

typedef const __attribute__((address_space(1))) void g_void;
typedef __attribute__((address_space(3))) void l_void;

__device__ __forceinline__ float b2f(u16 u) {
    union { unsigned int i; float f; } v; v.i = ((unsigned int)u) << 16; return v.f;
}
__device__ __forceinline__ u16 f2b(float f) {
    union { float f; unsigned int i; } v; v.f = f;
    unsigned int x = v.i;
    return (u16)((x + 0x7fffu + ((x >> 16) & 1u)) >> 16);
}
__device__ __forceinline__ float gelu_exact(float x) {
    return 0.5f * x * (1.0f + erff(x * 0.70710678118654752440f));
}

// ------------------------------------------------------------ dtype sniff
__global__ void sniff_kernel(const u16* __restrict__ x, int* __restrict__ flag) {
    int lane = threadIdx.x;
    int sane = 0;
    for (int i = lane * 2; i < 4096; i += 128) {
        int e = (x[i] >> 7) & 0xff;
        if (e >= 100 && e <= 140) sane++;
    }
#pragma unroll
    for (int off = 32; off; off >>= 1) sane += __shfl_xor(sane, off, 64);
    if (lane == 0) *flag = (sane * 2 >= 2048) ? 0 : 1;
}

// ------------------------------------------------------------ any -> bf16 canonical (ctx)
__global__ __launch_bounds__(256) void cvt_bf_kernel(const void* __restrict__ in,
                                                     u16* __restrict__ out, int n4,
                                                     const int* __restrict__ flag) {
    int i = blockIdx.x * 256 + threadIdx.x;
    if (i >= n4) return;
    bool isf = (*flag != 0);
    uint2 pk;
    if (isf) {
        float4 v = ((const float4*)in)[i];
        pk.x = (unsigned)f2b(v.x) | ((unsigned)f2b(v.y) << 16);
        pk.y = (unsigned)f2b(v.z) | ((unsigned)f2b(v.w) << 16);
    } else {
        pk = ((const uint2*)in)[i];
    }
    ((uint2*)out)[i] = pk;
}

// ------------------------------------------------------------ batched transpose+cast: 12 weights in one launch
struct TEnt { const void* src; u16* dst; int R, C, tiles_x, tiles; };
struct TPack { TEnt e[12]; };

__global__ __launch_bounds__(256) void transpose_batch_kernel(TPack p, const int* __restrict__ flag) {
    TEnt e = p.e[blockIdx.y];
    if ((int)blockIdx.x >= e.tiles) return;
    __shared__ u16 t[32][33];
    bool isf = (*flag != 0);
    int tx = threadIdx.x, ty = threadIdx.y;
    int c0 = (blockIdx.x % e.tiles_x) * 32;
    int r0 = (blockIdx.x / e.tiles_x) * 32;
#pragma unroll
    for (int i = 0; i < 4; i++) {
        size_t idx = (size_t)(r0 + ty + i * 8) * e.C + c0 + tx;
        t[ty + i * 8][tx] = isf ? f2b(((const float*)e.src)[idx]) : ((const u16*)e.src)[idx];
    }
    __syncthreads();
#pragma unroll
    for (int i = 0; i < 4; i++)
        e.dst[(size_t)(c0 + ty + i * 8) * e.R + r0 + tx] = t[tx][ty + i * 8];
}

// ------------------------------------------------------------ LayerNorm, row=1024
// raw=0: x fp32. raw=1: x is network input (dtype per flag) + writes fp32 copy to xout.
__global__ __launch_bounds__(256) void ln_kernel(const void* __restrict__ x,
                                                 float* __restrict__ xout,
                                                 const void* __restrict__ g,
                                                 const void* __restrict__ bb,
                                                 u16* __restrict__ out,
                                                 const int* __restrict__ flag,
                                                 int raw) {
    const int row = blockIdx.x;
    const int tid = threadIdx.x;
    const int lane = tid & 63, wave = tid >> 6;
    bool isf = (*flag != 0);
    size_t base = (size_t)row * 1024 + tid * 4;
    float4 xv;
    if (raw && !isf) {
        uint2 w = ((const uint2*)x)[base >> 2];
        xv.x = b2f((u16)(w.x & 0xffff)); xv.y = b2f((u16)(w.x >> 16));
        xv.z = b2f((u16)(w.y & 0xffff)); xv.w = b2f((u16)(w.y >> 16));
    } else {
        xv = ((const float4*)x)[base >> 2];
    }
    if (raw) ((float4*)xout)[base >> 2] = xv;
    float s  = xv.x + xv.y + xv.z + xv.w;
    float s2 = xv.x * xv.x + xv.y * xv.y + xv.z * xv.z + xv.w * xv.w;
#pragma unroll
    for (int off = 32; off; off >>= 1) {
        s  += __shfl_xor(s, off, 64);
        s2 += __shfl_xor(s2, off, 64);
    }
    __shared__ float red[8];
    if (lane == 0) { red[wave] = s; red[4 + wave] = s2; }
    __syncthreads();
    s  = red[0] + red[1] + red[2] + red[3];
    s2 = red[4] + red[5] + red[6] + red[7];
    const float inv_n = 1.0f / 1024.0f;
    float mean = s * inv_n;
    float var  = s2 * inv_n - mean * mean;
    float rstd = rsqrtf(var + 1e-5f);
    float gv[4], bv[4];
    if (isf) {
        float4 gg = *(const float4*)((const float*)g + tid * 4);
        float4 bo = *(const float4*)((const float*)bb + tid * 4);
        gv[0] = gg.x; gv[1] = gg.y; gv[2] = gg.z; gv[3] = gg.w;
        bv[0] = bo.x; bv[1] = bo.y; bv[2] = bo.z; bv[3] = bo.w;
    } else {
        uint2 go = *(const uint2*)((const u16*)g + tid * 4);
        uint2 bo = *(const uint2*)((const u16*)bb + tid * 4);
        gv[0] = b2f((u16)(go.x & 0xffff)); gv[1] = b2f((u16)(go.x >> 16));
        gv[2] = b2f((u16)(go.y & 0xffff)); gv[3] = b2f((u16)(go.y >> 16));
        bv[0] = b2f((u16)(bo.x & 0xffff)); bv[1] = b2f((u16)(bo.x >> 16));
        bv[2] = b2f((u16)(bo.y & 0xffff)); bv[3] = b2f((u16)(bo.y >> 16));
    }
    float xa[4] = { xv.x, xv.y, xv.z, xv.w };
    u16 o[4];
#pragma unroll
    for (int j = 0; j < 4; j++)
        o[j] = f2b((xa[j] - mean) * rstd * gv[j] + bv[j]);
    uint2 pk;
    pk.x = (unsigned)o[0] | ((unsigned)o[1] << 16);
    pk.y = (unsigned)o[2] | ((unsigned)o[3] << 16);
    *(uint2*)(out + base) = pk;
}

// ------------------------------------------------------------ GEMM: C[M,N] = A[M,K] * BT[N,K]^T + epilogue
// BM = MT*32, BN = NT*32, BK = 64*KH. KH sub-tiles each use the PROVEN
// conflict-free 64-elem-row layout (stride 128 B, mod-8 col-block swizzle
// phys=(log+row)&7 on both the DMA source and the fragment reads).
// MODE 0: bf16 out (+bias); 1: bf16 gelu(acc+bias); 2: f32 acc+bias+res; 3: final (bf16 or f32 by flag)
template <int MODE, int MT, int NT, int KH, int MINW>
__global__ __launch_bounds__(256, MINW) void gemm_kernel(const u16* __restrict__ A,
                                                         const u16* __restrict__ BT,
                                                         const void* __restrict__ bias,
                                                         const float* __restrict__ res,
                                                         void* __restrict__ Cout,
                                                         int M, int N, int K,
                                                         const int* __restrict__ flag) {
    __shared__ __align__(16) u16 lsA[MT * KH * 2048];
    __shared__ __align__(16) u16 lsB[NT * KH * 2048];
    const int tid = threadIdx.x;
    const int lane = tid & 63;
    const int wave = tid >> 6;
    const int wm = (wave >> 1) * (MT * 16);
    const int wn = (wave & 1) * (NT * 16);
    const int bm = blockIdx.y * (MT * 32);
    const int bn = blockIdx.x * (NT * 32);
    const int l16 = lane & 15;
    const int lq = lane >> 4;
    const bool isf = (*flag != 0);

    floatx4 acc[MT][NT] = {};

    const int r_in = tid >> 3;                      // 0..31 row within chunk
    const int cb_log = ((tid & 7) - r_in) & 7;      // phys col-block = tid & 7
    const int gcol = cb_log * 8;

    const u16* gA[MT];
#pragma unroll
    for (int j = 0; j < MT; j++) {
        int rr = bm + j * 32 + r_in; if (rr >= M) rr = M - 1;  // clamp: finite, never stored
        gA[j] = A + (size_t)rr * K + gcol;
    }
    const u16* gB[NT];
#pragma unroll
    for (int j = 0; j < NT; j++) {
        int rr = bn + j * 32 + r_in; if (rr >= N) rr = N - 1;
        gB[j] = BT + (size_t)rr * K + gcol;
    }

    for (int k0 = 0; k0 < K; k0 += 64 * KH) {
#pragma unroll
        for (int j = 0; j < MT; j++)
#pragma unroll
            for (int h = 0; h < KH; h++)
                __builtin_amdgcn_global_load_lds((g_void*)(gA[j] + k0 + h * 64),
                                                 (l_void*)(lsA + (j * KH + h) * 2048 + tid * 8), 16, 0, 0);
#pragma unroll
        for (int j = 0; j < NT; j++)
#pragma unroll
            for (int h = 0; h < KH; h++)
                __builtin_amdgcn_global_load_lds((g_void*)(gB[j] + k0 + h * 64),
                                                 (l_void*)(lsB + (j * KH + h) * 2048 + tid * 8), 16, 0, 0);
        __syncthreads();

#pragma unroll
        for (int ki = 0; ki < 2 * KH; ki++) {
            const int half = ki >> 1, kin = ki & 1;
            short8 af[MT], bf[NT];
#pragma unroll
            for (int mi = 0; mi < MT; mi++) {
                int ra = wm + mi * 16 + l16;
                af[mi] = *(const short8*)&lsA[((ra >> 5) * KH + half) * 2048 + (ra & 31) * 64
                                              + ((kin * 4 + lq + ra) & 7) * 8];
            }
#pragma unroll
            for (int ni = 0; ni < NT; ni++) {
                int rb = wn + ni * 16 + l16;
                bf[ni] = *(const short8*)&lsB[((rb >> 5) * KH + half) * 2048 + (rb & 31) * 64
                                              + ((kin * 4 + lq + rb) & 7) * 8];
            }
#pragma unroll
            for (int mi = 0; mi < MT; mi++)
#pragma unroll
                for (int ni = 0; ni < NT; ni++)
                    acc[mi][ni] = __builtin_amdgcn_mfma_f32_16x16x32_bf16(af[mi], bf[ni], acc[mi][ni], 0, 0, 0);
        }
        __syncthreads();
    }

#pragma unroll
    for (int mi = 0; mi < MT; mi++) {
#pragma unroll
        for (int ni = 0; ni < NT; ni++) {
            int col = bn + wn + ni * 16 + l16;
            float bv = 0.0f;
            if (bias) bv = isf ? ((const float*)bias)[col] : b2f(((const u16*)bias)[col]);
#pragma unroll
            for (int r = 0; r < 4; r++) {
                int row = bm + wm + mi * 16 + lq * 4 + r;
                if (row < M) {
                    float v = acc[mi][ni][r] + bv;
                    size_t idx = (size_t)row * N + col;
                    if (MODE == 1) v = gelu_exact(v);
                    if (MODE == 2 || MODE == 3) v += res[idx];
                    if (MODE == 2)       ((float*)Cout)[idx] = v;
                    else if (MODE == 3) { if (isf) ((float*)Cout)[idx] = v; else ((u16*)Cout)[idx] = f2b(v); }
                    else                 ((u16*)Cout)[idx] = f2b(v);
                }
            }
        }
    }
}

// ------------------------------------------------------------ MFMA flash attention v3: 128 q-rows/block
__global__ __launch_bounds__(256, 2) void attn_mfma_kernel(const u16* __restrict__ q,
                                                           const u16* __restrict__ k,
                                                           const u16* __restrict__ v,
                                                           u16* __restrict__ o,
                                                           int T, int S, int ldq, int ldkv,
                                                           float cexp) {
    const int E = 1024;
    const int b = blockIdx.y >> 4, h = blockIdx.y & 15;
    const int tid = threadIdx.x, wave = tid >> 6, lane = tid & 63;
    const int l16 = lane & 15, lq = lane >> 4;

    __shared__ __align__(16) u16 Qs[128 * 64];
    __shared__ __align__(16) u16 Ks[64 * 64];
    __shared__ __align__(16) u16 Vt[64 * 72];
    __shared__ __align__(16) u16 Ps[4][16 * 72];

    const int q0 = blockIdx.x * 128;
    const int r8 = tid >> 3;
    const int cb_log = ((tid & 7) - r8) & 7;
    const int rv = tid >> 2, cv = (tid & 3) * 16;
    const int cbv = ((rv >> 3) ^ (tid & 3)) & 7;

#pragma unroll
    for (int j = 0; j < 4; j++) {
        int row = q0 + j * 32 + r8;
        __builtin_amdgcn_global_load_lds((g_void*)(q + (size_t)(b * T + row) * ldq + h * 64 + cb_log * 8),
                                         (l_void*)(Qs + j * 2048 + tid * 8), 16, 0, 0);
    }
    __syncthreads();

    short8 af[2][2];
#pragma unroll
    for (int j = 0; j < 2; j++) {
        int qr = j * 64 + wave * 16 + l16;
        af[j][0] = *(const short8*)&Qs[qr * 64 + ((lq + qr) & 7) * 8];
        af[j][1] = *(const short8*)&Qs[qr * 64 + ((lq + 4 + qr) & 7) * 8];
    }

    float lsum[2][4] = {};
    floatx4 oacc[2][4] = {};

    const int ntiles = (S + 63) >> 6;
    for (int t = 0; t < ntiles; t++) {
        const int s0 = t * 64;
        __syncthreads();
#pragma unroll
        for (int j = 0; j < 2; j++) {
            int srow = s0 + j * 32 + r8; if (srow >= S) srow = S - 1;
            __builtin_amdgcn_global_load_lds((g_void*)(k + (size_t)(b * S + srow) * ldkv + h * 64 + cb_log * 8),
                                             (l_void*)(Ks + j * 2048 + tid * 8), 16, 0, 0);
        }
        {
            int sr = s0 + rv; if (sr >= S) sr = S - 1;
            const u16* vsrc = v + (size_t)(b * S + sr) * ldkv + h * 64 + cv;
            uint4 v0 = *(const uint4*)vsrc;
            uint4 v1 = *(const uint4*)(vsrc + 8);
            const u16* vp = (const u16*)&v0;
#pragma unroll
            for (int j = 0; j < 8; j++)
                Vt[(cv + j) * 72 + cbv * 8 + (rv & 7)] = vp[j];
            vp = (const u16*)&v1;
#pragma unroll
            for (int j = 0; j < 8; j++)
                Vt[(cv + 8 + j) * 72 + cbv * 8 + (rv & 7)] = vp[j];
        }
        __syncthreads();

        const bool tail = (s0 + 64 > S);
#pragma unroll
        for (int j = 0; j < 2; j++) {
            floatx4 sc[4];
#pragma unroll
            for (int nt = 0; nt < 4; nt++) {
                int krow = nt * 16 + l16;
                short8 bf0 = *(const short8*)&Ks[krow * 64 + ((lq + krow) & 7) * 8];
                short8 bf1 = *(const short8*)&Ks[krow * 64 + ((lq + 4 + krow) & 7) * 8];
                floatx4 z = {};
                z = __builtin_amdgcn_mfma_f32_16x16x32_bf16(af[j][0], bf0, z, 0, 0, 0);
                z = __builtin_amdgcn_mfma_f32_16x16x32_bf16(af[j][1], bf1, z, 0, 0, 0);
                sc[nt] = z;
            }
#pragma unroll
            for (int nt = 0; nt < 4; nt++) {
                bool colv = !tail || (s0 + nt * 16 + l16 < S);
#pragma unroll
                for (int r = 0; r < 4; r++) {
                    float p = exp2f(sc[nt][r] * cexp);
                    p = colv ? p : 0.0f;
                    lsum[j][r] += p;
                    Ps[wave][(lq * 4 + r) * 72 + nt * 16 + l16] = f2b(p);
                }
            }
            short8 av0 = *(const short8*)&Ps[wave][l16 * 72 + lq * 8];
            short8 av1 = *(const short8*)&Ps[wave][l16 * 72 + 32 + lq * 8];
#pragma unroll
            for (int dt = 0; dt < 4; dt++) {
                int d = dt * 16 + l16;
                short8 bv0 = *(const short8*)&Vt[d * 72 + ((lq ^ dt) & 7) * 8];
                short8 bv1 = *(const short8*)&Vt[d * 72 + (((4 + lq) ^ dt) & 7) * 8];
                oacc[j][dt] = __builtin_amdgcn_mfma_f32_16x16x32_bf16(av0, bv0, oacc[j][dt], 0, 0, 0);
                oacc[j][dt] = __builtin_amdgcn_mfma_f32_16x16x32_bf16(av1, bv1, oacc[j][dt], 0, 0, 0);
            }
        }
    }

#pragma unroll
    for (int j = 0; j < 2; j++)
#pragma unroll
        for (int r = 0; r < 4; r++) {
#pragma unroll
            for (int off = 1; off < 16; off <<= 1)
                lsum[j][r] += __shfl_xor(lsum[j][r], off, 64);
        }

#pragma unroll
    for (int j = 0; j < 2; j++)
#pragma unroll
        for (int r = 0; r < 4; r++) {
            float inv = 1.0f / lsum[j][r];
            int row = q0 + j * 64 + wave * 16 + lq * 4 + r;
            u16* dst = o + (size_t)(b * T + row) * E + h * 64 + l16;
#pragma unroll
            for (int dt = 0; dt < 4; dt++)
                dst[dt * 16] = f2b(oacc[j][dt][r] * inv);
        }
}

// ------------------------------------------------------------ host
extern "C" void kernel_launch(void* const* d_in, const int* in_sizes, int n_in,
                              void* d_out, int out_size, void* d_ws, size_t ws_size,
                              hipStream_t stream) {
    const void* x_in = d_in[0];
    const void* ctx  = d_in[1];
    const void* sq_w = d_in[2];
    const void* sk_w = d_in[3];
    const void* sv_w = d_in[4];
    const void* so_w = d_in[5];
    const void* so_b = d_in[6];
    const void* cq_w = d_in[7];
    const void* ck_w = d_in[8];
    const void* cv_w = d_in[9];
    const void* co_w = d_in[10];
    const void* co_b = d_in[11];
    const void* n1_g = d_in[12];
    const void* n1_b = d_in[13];
    const void* n2_g = d_in[14];
    const void* n2_b = d_in[15];
    const void* n3_g = d_in[16];
    const void* n3_b = d_in[17];
    const void* n4_g = d_in[18];
    const void* n4_b = d_in[19];
    const void* f1_w1 = d_in[20];
    const void* f1_b1 = d_in[21];
    const void* f1_w2 = d_in[22];
    const void* f1_b2 = d_in[23];
    const void* f2_w1 = d_in[24];
    const void* f2_b1 = d_in[25];
    const void* f2_w2 = d_in[26];
    const void* f2_b2 = d_in[27];

    const int B = 4, T = 1024, H = 1024, FF = 4096, CD = 768, S = 77;
    const int BT_ = B * T;   // 4096
    const int BS_ = B * S;   // 308

    char* ws = (char*)d_ws;
    size_t off = 0;
    auto alloc = [&](size_t bytes) { char* p = ws + off; off += (bytes + 255) & ~(size_t)255; return p; };
    int*   flag = (int*)alloc(256);
    u16*   ctxb = (u16*)alloc((size_t)BS_ * CD * 2);
    float* xcur = (float*)alloc((size_t)BT_ * H * 4);
    const size_t MEL = 1024 * 1024;
    u16* wqkv = (u16*)alloc(3 * MEL * 2);
    u16* wso  = (u16*)alloc(MEL * 2);
    u16* wcq  = (u16*)alloc(MEL * 2);
    u16* wckv = (u16*)alloc((size_t)2 * H * CD * 2);
    u16* wco  = (u16*)alloc(MEL * 2);
    u16* wf1a = (u16*)alloc((size_t)H * FF * 2);
    u16* wf1b = (u16*)alloc((size_t)H * FF * 2);
    u16* wf2a = (u16*)alloc((size_t)H * FF * 2);
    u16* wf2b = (u16*)alloc((size_t)H * FF * 2);
    u16* U    = (u16*)alloc((size_t)40 * 1024 * 1024);
    (void)ws_size; (void)n_in; (void)in_sizes; (void)out_size;

    const size_t AEL = (size_t)BT_ * H;
    u16* lnb  = U;
    u16* qkvb = U + AEL;
    u16* ob   = U + 4 * AEL;
    u16* hb   = U + AEL;
    u16* qb   = U + AEL;
    u16* kvb  = U + 2 * AEL;

    TPack tp;
    auto ent = [&](int i, const void* src, u16* dst, int R, int C) {
        tp.e[i] = TEnt{ src, dst, R, C, C / 32, (C / 32) * (R / 32) };
    };
    ent(0,  sq_w, wqkv,           H,  H);
    ent(1,  sk_w, wqkv + MEL,     H,  H);
    ent(2,  sv_w, wqkv + 2 * MEL, H,  H);
    ent(3,  so_w, wso,            H,  H);
    ent(4,  cq_w, wcq,            H,  H);
    ent(5,  ck_w, wckv,           CD, H);
    ent(6,  cv_w, wckv + (size_t)H * CD, CD, H);
    ent(7,  co_w, wco,            H,  H);
    ent(8,  f1_w1, wf1a,          H,  FF);
    ent(9,  f1_w2, wf1b,          FF, H);
    ent(10, f2_w1, wf2a,          H,  FF);
    ent(11, f2_w2, wf2b,          FF, H);

    const dim3 g_qkv(3072 / 128, BT_ / 128);         // 24 x 32
    const dim3 g_ff(FF / 128, BT_ / 128);            // 32 x 32
    const dim3 g_n1024(H / 128, BT_ / 64);           // 8 x 64 = 512 blocks (BN=128)
    const dim3 g_ckv(2048 / 128, (BS_ + 63) / 64);   // 16 x 5
    const dim3 attn_grid(T / 128, B * 16);
    const float cexp = 0.125f * 1.4426950408889634f;

    sniff_kernel<<<1, 64, 0, stream>>>((const u16*)x_in, flag);
    cvt_bf_kernel<<<(BS_ * CD / 4 + 255) / 256, 256, 0, stream>>>(ctx, ctxb, BS_ * CD / 4, flag);
    transpose_batch_kernel<<<dim3(4096, 12), dim3(32, 8), 0, stream>>>(tp, flag);

    // ---- self-attention block
    ln_kernel<<<BT_, 256, 0, stream>>>(x_in, xcur, n1_g, n1_b, lnb, flag, 1);
    gemm_kernel<0, 4, 4, 1, 3><<<g_qkv, 256, 0, stream>>>(lnb, wqkv, nullptr, nullptr, qkvb, BT_, 3072, H, flag);
    attn_mfma_kernel<<<attn_grid, 256, 0, stream>>>(qkvb, qkvb + 1024, qkvb + 2048, ob, T, T, 3072, 3072, cexp);
    gemm_kernel<2, 2, 4, 2, 3><<<g_n1024, 256, 0, stream>>>(ob, wso, so_b, xcur, xcur, BT_, H, H, flag);

    // ---- FFN 1
    ln_kernel<<<BT_, 256, 0, stream>>>(xcur, nullptr, n2_g, n2_b, lnb, flag, 0);
    gemm_kernel<1, 4, 4, 1, 3><<<g_ff, 256, 0, stream>>>(lnb, wf1a, f1_b1, nullptr, hb, BT_, FF, H, flag);
    gemm_kernel<2, 2, 4, 2, 3><<<g_n1024, 256, 0, stream>>>(hb, wf1b, f1_b2, xcur, xcur, BT_, H, FF, flag);

    // ---- cross-attention block
    ln_kernel<<<BT_, 256, 0, stream>>>(xcur, nullptr, n3_g, n3_b, lnb, flag, 0);
    gemm_kernel<0, 2, 4, 2, 3><<<g_n1024, 256, 0, stream>>>(lnb, wcq, nullptr, nullptr, qb, BT_, H, H, flag);
    gemm_kernel<0, 2, 4, 2, 3><<<g_ckv, 256, 0, stream>>>(ctxb, wckv, nullptr, nullptr, kvb, BS_, 2048, CD, flag);
    attn_mfma_kernel<<<attn_grid, 256, 0, stream>>>(qb, kvb, kvb + 1024, ob, T, S, 1024, 2048, cexp);
    gemm_kernel<2, 2, 4, 2, 3><<<g_n1024, 256, 0, stream>>>(ob, wco, co_b, xcur, xcur, BT_, H, H, flag);

    // ---- FFN 2 (final output -> d_out)
    ln_kernel<<<BT_, 256, 0, stream>>>(xcur, nullptr, n4_g, n4_b, lnb, flag, 0);
    gemm_kernel<1, 4, 4, 1, 3><<<g_ff, 256, 0, stream>>>(lnb, wf2a, f2_b1, nullptr, hb, BT_, FF, H, flag);
    gemm_kernel<3, 2, 4, 2, 3><<<g_n1024, 256, 0, stream>>>(hb, wf2b, f2_b2, xcur, d_out, BT_, H, FF, flag);
}